// Round 15
// baseline (70.107 us; speedup 1.0000x reference)
//
#include <hip/hip_runtime.h>
#include <math.h>

#define NLEV   16
#define TSIZE  524288
#define TMASK  524287
#define NPIX   (1024*1024)
#define NCORN  908          // sum of Wc^2 over 16 levels
#define MAP_F_OFF 3600      // map table at ws float-offset 3600 (byte 14400)

typedef __attribute__((ext_vector_type(8))) short s8v;
typedef __attribute__((ext_vector_type(4))) float f4v;
typedef __attribute__((ext_vector_type(2))) float f2v;

struct ResArr { float r[NLEV]; };
union Frag { unsigned int u[4]; s8v v; };

// Per-level corner-grid width for a 16x16-px block: Wc = floor(15*res/1024)+3
// (covers worst-case cell crossing + the +1 corner); level 15 is exact-integer
// (res=1024, frac==0) and needs exactly 17. res = [16,21,27,36,48,63,84,111,
// 147,194,256,337,445,588,776,1024].
#define WC0 3
#define WC_LIST  {3,3,3,3,3,3,4,4,5,5,6,7,9,11,14,17}
#define OFF_LIST {0,9,18,27,36,45,54,70,86,111,136,172,221,302,423,619}

__device__ __forceinline__ unsigned short bf16_rn(float x) {
    unsigned int u = __builtin_bit_cast(unsigned int, x);
    u += 0x7fffu + ((u >> 16) & 1u);
    return (unsigned short)(u >> 16);
}
// truncating bf16 pack: one v_perm_b32 (values ~1e-4 vs 1e-2 threshold).
__device__ __forceinline__ unsigned int pk_bf16(float lo, float hi) {
    return __builtin_amdgcn_perm(__builtin_bit_cast(unsigned int, hi),
                                 __builtin_bit_cast(unsigned int, lo),
                                 0x07060302u);
}

// ws layout: [0..15] res f32. ushort region at ws+16: w1t [64][32], w2t
// k-permuted [64][64], w3t k-permuted row-replicated [16][64] (ends at byte
// 14400). u32 map[NCORN] at float-offset 3600: (level<<16)|(jj<<8)|ii for
// each flat corner slot -> branch-free LDS staging in the fused kernel.
__global__ __launch_bounds__(256) void prep_kernel(
    const float* __restrict__ W1, const float* __restrict__ W2,
    const float* __restrict__ W3, float* __restrict__ ws, ResArr res)
{
    const int t = threadIdx.x;
    if (t < NLEV) ws[t] = res.r[t];
    unsigned short* w1t = (unsigned short*)(ws + 16);
    unsigned short* w2t = w1t + 64 * 32;
    unsigned short* w3t = w2t + 64 * 64;
    unsigned int*   map = (unsigned int*)(ws + MAP_F_OFF);
    for (int i = t; i < 64 * 32; i += 256) {
        int n = i >> 5, k = i & 31;
        w1t[i] = bf16_rn(W1[k * 64 + n]);
    }
    for (int i = t; i < 64 * 64; i += 256) {
        int n2 = i >> 6, kp = i & 63;
        int klog = (kp & 32) | ((kp & 4) << 2) | ((kp & 24) >> 1) | (kp & 3);
        w2t[i] = bf16_rn(W2[klog * 64 + n2]);
    }
    for (int i = t; i < 16 * 64; i += 256) {
        int row = i >> 6, kp = i & 63;
        int klog = (kp & 32) | ((kp & 4) << 2) | ((kp & 24) >> 1) | (kp & 3);
        int ch = row & 3;
        w3t[i] = (ch < 3) ? bf16_rn(W3[klog * 3 + ch]) : (unsigned short)0;
    }
    constexpr int WCc[16]  = WC_LIST;
    constexpr int OFFc[16] = OFF_LIST;
    for (int i = t; i < NCORN; i += 256) {
        int l = 0, off = 0, wc = WC0;
        #pragma unroll
        for (int k = 1; k < 16; ++k)
            if (i >= OFFc[k]) { l = k; off = OFFc[k]; wc = WCc[k]; }
        const int loc = i - off;
        const int jj  = loc / wc;       // prep-only runtime div: fine
        const int ii  = loc - jj * wc;
        map[i] = ((unsigned int)l << 16) | ((unsigned int)jj << 8)
               | (unsigned int)ii;
    }
}

// R8-R14 evidence chain: encode floor (~45us) is invariant to occupancy
// (34->62%), load-batch depth (2->32), VALU stream (-25%: R14 null) -> it is
// the memory-pipe cost of 64 scattered global-gather INSTRUCTIONS per wave
// (~26 cyc each). R12/R13's partial-staging nulls were confounded by
// divergent dual paths. This kernel: stage ALL 908 unique corners of the
// block (7.3 KB) with ~8 VMEM instr/wave, then every lane bilerps all 16
// levels from LDS (ds_read_b64 scattered ~6-10 cyc) -- no divergence.
__global__ __launch_bounds__(256) void ngp_fused_kernel(
    const float* __restrict__ tables,
    const float* __restrict__ b1, const float* __restrict__ b2,
    const float* __restrict__ b3,
    const float* __restrict__ ws, float* __restrict__ out)
{
    __shared__ float2 ldsc[NCORN];

    const int tid  = threadIdx.x;
    const int lane = tid & 63;
    const int wv   = tid >> 6;
    const int c15  = lane & 15;
    const int g    = lane >> 4;
    const int xb   = blockIdx.x * 16;
    const int yb   = blockIdx.y * 16;

    const float xbf = (float)xb * (1.0f / 1024.0f);
    const float ybf = (float)yb * (1.0f / 1024.0f);

    // ---- stage all 16 levels' corner grids into LDS (branch-free) ----
    {
        const unsigned int* __restrict__ map =
            (const unsigned int*)(ws + MAP_F_OFF);
        const float2* __restrict__ tabs = (const float2*)tables;
        for (int i = tid; i < NCORN; i += 256) {
            const unsigned int m = map[i];
            const int l  = (int)(m >> 16);
            const int jj = (int)((m >> 8) & 255u);
            const int ii = (int)(m & 255u);
            const float r = ws[l];
            const int cx0 = (int)floorf(xbf * r);   // exact: xb*r < 2^20
            const int cy0 = (int)floorf(ybf * r);
            const unsigned int idx =
                (((unsigned int)(cx0 + ii)) ^
                 ((unsigned int)(cy0 + jj) * 2654435761u)) & TMASK;
            ldsc[i] = tabs[((size_t)l << 19) + idx];
        }
    }
    __syncthreads();

    const float4 rv = *(const float4*)(ws + g * 4);
    const float rr[4] = { rv.x, rv.y, rv.z, rv.w };
    const float xs = (float)(xb + c15) * (1.0f / 1024.0f);
    float yf[4];
    #pragma unroll
    for (int pt = 0; pt < 4; ++pt)
        yf[pt] = (float)(yb + wv * 4 + pt) * (1.0f / 1024.0f);

    // ---- encode: all levels from LDS; lerp-form packed bilerp ----
    constexpr int WCc[16]  = WC_LIST;
    constexpr int OFFc[16] = OFF_LIST;
    Frag bfrag[4];
    #pragma unroll
    for (int j = 0; j < 4; ++j) {
        int wc  = WCc[j];      int off = OFFc[j];
        wc  = (g == 1) ? WCc[4 + j]  : wc;  off = (g == 1) ? OFFc[4 + j]  : off;
        wc  = (g == 2) ? WCc[8 + j]  : wc;  off = (g == 2) ? OFFc[8 + j]  : off;
        wc  = (g == 3) ? WCc[12 + j] : wc;  off = (g == 3) ? OFFc[12 + j] : off;
        const float r   = rr[j];
        const float sx  = xs * r;
        const float fx0 = floorf(sx);
        const float fx  = sx - fx0;
        const f2v  fx2  = { fx, fx };
        const int ii    = (int)fx0 - (int)floorf(xbf * r);
        const int cy0i  = (int)floorf(ybf * r);
        const int rowb  = off + ii;
        #pragma unroll
        for (int pt = 0; pt < 4; ++pt) {
            const float sy  = yf[pt] * r;
            const float fy0 = floorf(sy);
            const float fy  = sy - fy0;
            const f2v  fy2  = { fy, fy };
            const int jj    = (int)fy0 - cy0i;
            const int base  = rowb + jj * wc;
            const f2v c00 = *(const f2v*)&ldsc[base];
            const f2v c10 = *(const f2v*)&ldsc[base + 1];
            const f2v c01 = *(const f2v*)&ldsc[base + wc];
            const f2v c11 = *(const f2v*)&ldsc[base + wc + 1];
            const f2v top = c00 + fx2 * (c10 - c00);
            const f2v bot = c01 + fx2 * (c11 - c01);
            const f2v e   = top + fy2 * (bot - top);
            bfrag[pt].u[j] = pk_bf16(e[0], e[1]);
        }
    }

    const unsigned short* __restrict__ w1t = (const unsigned short*)(ws + 16);
    const unsigned short* __restrict__ w2t = w1t + 64 * 32;
    const unsigned short* __restrict__ w3t = w2t + 64 * 64;
    const f4v zero4 = { 0.f, 0.f, 0.f, 0.f };

    // ---- layer 1: packed epilogue, write straight into layer-2 B-frags ----
    Frag hp2[2][4];   // [st][pt]
    #pragma unroll
    for (int mt = 0; mt < 4; ++mt) {
        Frag afr;
        afr.v = *(const s8v*)(w1t + (mt * 16 + c15) * 32 + g * 8);
        const f4v bb = *(const f4v*)(b1 + mt * 16 + g * 4);
        #pragma unroll
        for (int pt = 0; pt < 4; ++pt) {
            f4v acc = zero4;
            acc = __builtin_amdgcn_mfma_f32_16x16x32_bf16(
                afr.v, bfrag[pt].v, acc, 0, 0, 0);
            const f4v hv = __builtin_elementwise_max(acc + bb, zero4);
            hp2[mt >> 1][pt].u[(mt & 1) * 2 + 0] = pk_bf16(hv[0], hv[1]);
            hp2[mt >> 1][pt].u[(mt & 1) * 2 + 1] = pk_bf16(hv[2], hv[3]);
        }
    }

    // ---- layer 2: B-frags are hp2[st][pt] directly (k-permuted W2) ----
    Frag hq2[2][4];
    #pragma unroll
    for (int mt = 0; mt < 4; ++mt) {
        const f4v bb2 = *(const f4v*)(b2 + mt * 16 + g * 4);
        f4v acc[4] = { zero4, zero4, zero4, zero4 };
        #pragma unroll
        for (int st = 0; st < 2; ++st) {
            Frag a2;
            a2.v = *(const s8v*)(w2t + (mt * 16 + c15) * 64 + st * 32 + g * 8);
            #pragma unroll
            for (int pt = 0; pt < 4; ++pt)
                acc[pt] = __builtin_amdgcn_mfma_f32_16x16x32_bf16(
                    a2.v, hp2[st][pt].v, acc[pt], 0, 0, 0);
        }
        #pragma unroll
        for (int pt = 0; pt < 4; ++pt) {
            const f4v hv = __builtin_elementwise_max(acc[pt] + bb2, zero4);
            hq2[mt >> 1][pt].u[(mt & 1) * 2 + 0] = pk_bf16(hv[0], hv[1]);
            hq2[mt >> 1][pt].u[(mt & 1) * 2 + 1] = pk_bf16(hv[2], hv[3]);
        }
    }

    // ---- layer 3 on MFMA (row-replicated W3: reg r = channel r) ----
    f4v acc3[4] = { zero4, zero4, zero4, zero4 };
    #pragma unroll
    for (int st = 0; st < 2; ++st) {
        Frag a3;
        a3.v = *(const s8v*)(w3t + c15 * 64 + st * 32 + g * 8);
        #pragma unroll
        for (int pt = 0; pt < 4; ++pt)
            acc3[pt] = __builtin_amdgcn_mfma_f32_16x16x32_bf16(
                a3.v, hq2[st][pt].v, acc3[pt], 0, 0, 0);
    }

    float ov[3];
    #pragma unroll
    for (int c = 0; c < 3; ++c) {
        float v = acc3[0][c];
        v = (g == 1) ? acc3[1][c] : v;
        v = (g == 2) ? acc3[2][c] : v;
        v = (g == 3) ? acc3[3][c] : v;
        ov[c] = v + b3[c];
    }
    const int pix = ((yb + wv * 4 + g) << 10) + xb + c15;
    out[0 * NPIX + pix] = 1.0f / (1.0f + __expf(-ov[0]));
    out[1 * NPIX + pix] = 1.0f / (1.0f + __expf(-ov[1]));
    out[2 * NPIX + pix] = 1.0f / (1.0f + __expf(-ov[2]));
}

extern "C" void kernel_launch(void* const* d_in, const int* in_sizes, int n_in,
                              void* d_out, int out_size, void* d_ws, size_t ws_size,
                              hipStream_t stream) {
    const float* tables = (const float*)d_in[0];
    const float* W1     = (const float*)d_in[1];
    const float* b1     = (const float*)d_in[2];
    const float* W2     = (const float*)d_in[3];
    const float* b2     = (const float*)d_in[4];
    const float* W3     = (const float*)d_in[5];
    const float* b3     = (const float*)d_in[6];
    float* out          = (float*)d_out;
    float* ws           = (float*)d_ws;

    ResArr res;
    const double growth = exp((log(1024.0) - log(16.0)) / 15.0);
    for (int l = 0; l < NLEV; ++l)
        res.r[l] = (float)floor(16.0 * pow(growth, (double)l));

    hipLaunchKernelGGL(prep_kernel, dim3(1), dim3(256), 0, stream, W1, W2, W3, ws, res);
    hipLaunchKernelGGL(ngp_fused_kernel, dim3(64, 64), dim3(256), 0, stream,
                       tables, b1, b2, b3, ws, out);
}

// Round 16
// 69.771 us; speedup vs baseline: 1.0048x; 1.0048x over previous
//
#include <hip/hip_runtime.h>
#include <math.h>

#define NLEV   16
#define TSIZE  524288
#define TMASK  524287
#define NPIX   (1024*1024)
#define NWC    448          // padded per-wave corner slots (405 real)
#define MAP_F_OFF 3600      // map table at ws float-offset 3600 (byte 14400)

typedef __attribute__((ext_vector_type(8))) short s8v;
typedef __attribute__((ext_vector_type(4))) float f4v;
typedef __attribute__((ext_vector_type(2))) float f2v;

struct ResArr { float r[NLEV]; };
union Frag { unsigned int u[4]; s8v v; };

// Per-WAVE (16x4 px) corner grids: Wcx = floor(15*res/1024)+3,
// Wcy = floor(3*res/1024)+3 (span + (+1)-corner + f32 slack; same accounting
// as R13's refcheck-passing geometry).
// res = [16,21,27,36,48,63,84,111,147,194,256,337,445,588,776,1024]
#define WCX_LIST {3,3,3,3,3,3,4,4,5,5,6,7,9,11,14,18}
#define WCY_LIST {3,3,3,3,3,3,3,3,3,3,3,3,4,4,5,6}
#define OFF_LIST {0,9,18,27,36,45,54,66,78,93,108,126,147,183,227,297}
// sizes: 9*6, 12*2, 15*2, 18, 21, 36, 44, 70, 108 -> total 405

__device__ __forceinline__ unsigned short bf16_rn(float x) {
    unsigned int u = __builtin_bit_cast(unsigned int, x);
    u += 0x7fffu + ((u >> 16) & 1u);
    return (unsigned short)(u >> 16);
}
// truncating bf16 pack: one v_perm_b32 (values ~1e-4 vs 1e-2 threshold).
__device__ __forceinline__ unsigned int pk_bf16(float lo, float hi) {
    return __builtin_amdgcn_perm(__builtin_bit_cast(unsigned int, hi),
                                 __builtin_bit_cast(unsigned int, lo),
                                 0x07060302u);
}

// ws layout: [0..15] res f32. ushort region at ws+16: w1t [64][32], w2t
// k-permuted [64][64], w3t k-permuted row-replicated [16][64]. u32 map[NWC]
// at float-offset MAP_F_OFF: (level<<16)|(jj<<8)|ii per per-wave corner slot
// (slots >=405 alias slot 0 -> harmless restage).
__global__ __launch_bounds__(256) void prep_kernel(
    const float* __restrict__ W1, const float* __restrict__ W2,
    const float* __restrict__ W3, float* __restrict__ ws, ResArr res)
{
    const int t = threadIdx.x;
    if (t < NLEV) ws[t] = res.r[t];
    unsigned short* w1t = (unsigned short*)(ws + 16);
    unsigned short* w2t = w1t + 64 * 32;
    unsigned short* w3t = w2t + 64 * 64;
    unsigned int*   map = (unsigned int*)(ws + MAP_F_OFF);
    for (int i = t; i < 64 * 32; i += 256) {
        int n = i >> 5, k = i & 31;
        w1t[i] = bf16_rn(W1[k * 64 + n]);
    }
    for (int i = t; i < 64 * 64; i += 256) {
        int n2 = i >> 6, kp = i & 63;
        int klog = (kp & 32) | ((kp & 4) << 2) | ((kp & 24) >> 1) | (kp & 3);
        w2t[i] = bf16_rn(W2[klog * 64 + n2]);
    }
    for (int i = t; i < 16 * 64; i += 256) {
        int row = i >> 6, kp = i & 63;
        int klog = (kp & 32) | ((kp & 4) << 2) | ((kp & 24) >> 1) | (kp & 3);
        int ch = row & 3;
        w3t[i] = (ch < 3) ? bf16_rn(W3[klog * 3 + ch]) : (unsigned short)0;
    }
    constexpr int WCXc[16] = WCX_LIST;
    constexpr int OFFc[16] = OFF_LIST;
    for (int i = t; i < NWC; i += 256) {
        unsigned int m = 0;
        if (i < 405) {
            int l = 0, off = 0, wc = 3;
            #pragma unroll
            for (int k = 1; k < 16; ++k)
                if (i >= OFFc[k]) { l = k; off = OFFc[k]; wc = WCXc[k]; }
            const int loc = i - off;
            const int jj  = loc / wc;
            const int ii  = loc - jj * wc;
            m = ((unsigned int)l << 16) | ((unsigned int)jj << 8)
              | (unsigned int)ii;
        }
        map[i] = m;
    }
}

// WAVE-PRIVATE staging, no barrier, no divergence.
// R8-R15 evidence: encode floor tracks scattered memory lane-addresses
// (invariant to occupancy, load depth, VALU stream, unique-line traffic;
// R15's block staging failed on barrier serialization at 20% occupancy).
// Here each wave stages its OWN 405 corners (7 scattered gathers + 7
// ds_write_b64, 448 lane-addresses vs 4096) into a private 3.5 KB LDS
// region, then bilerps all 16 levels from LDS. Same-wave ds visibility
// needs only lgkmcnt (compiler-inserted) -- zero __syncthreads.
__global__ __launch_bounds__(256) void ngp_fused_kernel(
    const float* __restrict__ tables,
    const float* __restrict__ b1, const float* __restrict__ b2,
    const float* __restrict__ b3,
    const float* __restrict__ ws, float* __restrict__ out)
{
    __shared__ float2 ldsw[4][NWC];   // 14,336 B

    const int tid  = threadIdx.x;
    const int lane = tid & 63;
    const int wv   = tid >> 6;
    const int c15  = lane & 15;
    const int g    = lane >> 4;
    const int xb   = blockIdx.x * 16;
    const int yb   = blockIdx.y * 16;
    const int yw   = yb + wv * 4;

    const float xbf = (float)xb * (1.0f / 1024.0f);
    const float ywf = (float)yw * (1.0f / 1024.0f);

    // ---- stage this wave's 16-level corner set (7 scattered gathers) ----
    {
        const unsigned int* __restrict__ map =
            (const unsigned int*)(ws + MAP_F_OFF);
        const float2* __restrict__ tabs = (const float2*)tables;
        float2* __restrict__ dst = &ldsw[wv][0];
        #pragma unroll
        for (int it = 0; it < 7; ++it) {
            const int s = it * 64 + lane;
            const unsigned int m = map[s];
            const int l  = (int)(m >> 16);
            const int jj = (int)((m >> 8) & 255u);
            const int ii = (int)(m & 255u);
            const float r = ws[l];
            const int cx0 = (int)floorf(xbf * r);
            const int cy0 = (int)floorf(ywf * r);
            const unsigned int idx =
                (((unsigned int)(cx0 + ii)) ^
                 ((unsigned int)(cy0 + jj) * 2654435761u)) & TMASK;
            dst[s] = tabs[((size_t)l << 19) + idx];
        }
    }

    const float4 rv = *(const float4*)(ws + g * 4);
    const float rr[4] = { rv.x, rv.y, rv.z, rv.w };
    const float xs = (float)(xb + c15) * (1.0f / 1024.0f);
    float yf[4];
    #pragma unroll
    for (int pt = 0; pt < 4; ++pt)
        yf[pt] = (float)(yw + pt) * (1.0f / 1024.0f);

    // ---- encode: all 16 levels from wave-private LDS ----
    constexpr int WCXc[16] = WCX_LIST;
    constexpr int OFFc[16] = OFF_LIST;
    const float2* __restrict__ lw = &ldsw[wv][0];
    Frag bfrag[4];
    #pragma unroll
    for (int j = 0; j < 4; ++j) {
        int wc  = WCXc[j];     int off = OFFc[j];
        wc  = (g == 1) ? WCXc[4 + j]  : wc;  off = (g == 1) ? OFFc[4 + j]  : off;
        wc  = (g == 2) ? WCXc[8 + j]  : wc;  off = (g == 2) ? OFFc[8 + j]  : off;
        wc  = (g == 3) ? WCXc[12 + j] : wc;  off = (g == 3) ? OFFc[12 + j] : off;
        const float r   = rr[j];
        const float sx  = xs * r;
        const float fx0 = floorf(sx);
        const float fx  = sx - fx0;
        const f2v  fx2  = { fx, fx };
        const int ii    = (int)fx0 - (int)floorf(xbf * r);
        const int cy0i  = (int)floorf(ywf * r);
        const int rowb  = off + ii;
        #pragma unroll
        for (int pt = 0; pt < 4; ++pt) {
            const float sy  = yf[pt] * r;
            const float fy0 = floorf(sy);
            const float fy  = sy - fy0;
            const f2v  fy2  = { fy, fy };
            const int jj    = (int)fy0 - cy0i;
            const int base  = rowb + jj * wc;
            const f2v c00 = *(const f2v*)&lw[base];
            const f2v c10 = *(const f2v*)&lw[base + 1];
            const f2v c01 = *(const f2v*)&lw[base + wc];
            const f2v c11 = *(const f2v*)&lw[base + wc + 1];
            const f2v top = c00 + fx2 * (c10 - c00);
            const f2v bot = c01 + fx2 * (c11 - c01);
            const f2v e   = top + fy2 * (bot - top);
            bfrag[pt].u[j] = pk_bf16(e[0], e[1]);
        }
    }

    const unsigned short* __restrict__ w1t = (const unsigned short*)(ws + 16);
    const unsigned short* __restrict__ w2t = w1t + 64 * 32;
    const unsigned short* __restrict__ w3t = w2t + 64 * 64;
    const f4v zero4 = { 0.f, 0.f, 0.f, 0.f };

    // ---- layer 1: packed epilogue, write straight into layer-2 B-frags ----
    Frag hp2[2][4];   // [st][pt]
    #pragma unroll
    for (int mt = 0; mt < 4; ++mt) {
        Frag afr;
        afr.v = *(const s8v*)(w1t + (mt * 16 + c15) * 32 + g * 8);
        const f4v bb = *(const f4v*)(b1 + mt * 16 + g * 4);
        #pragma unroll
        for (int pt = 0; pt < 4; ++pt) {
            f4v acc = zero4;
            acc = __builtin_amdgcn_mfma_f32_16x16x32_bf16(
                afr.v, bfrag[pt].v, acc, 0, 0, 0);
            const f4v hv = __builtin_elementwise_max(acc + bb, zero4);
            hp2[mt >> 1][pt].u[(mt & 1) * 2 + 0] = pk_bf16(hv[0], hv[1]);
            hp2[mt >> 1][pt].u[(mt & 1) * 2 + 1] = pk_bf16(hv[2], hv[3]);
        }
    }

    // ---- layer 2: B-frags are hp2[st][pt] directly (k-permuted W2) ----
    Frag hq2[2][4];
    #pragma unroll
    for (int mt = 0; mt < 4; ++mt) {
        const f4v bb2 = *(const f4v*)(b2 + mt * 16 + g * 4);
        f4v acc[4] = { zero4, zero4, zero4, zero4 };
        #pragma unroll
        for (int st = 0; st < 2; ++st) {
            Frag a2;
            a2.v = *(const s8v*)(w2t + (mt * 16 + c15) * 64 + st * 32 + g * 8);
            #pragma unroll
            for (int pt = 0; pt < 4; ++pt)
                acc[pt] = __builtin_amdgcn_mfma_f32_16x16x32_bf16(
                    a2.v, hp2[st][pt].v, acc[pt], 0, 0, 0);
        }
        #pragma unroll
        for (int pt = 0; pt < 4; ++pt) {
            const f4v hv = __builtin_elementwise_max(acc[pt] + bb2, zero4);
            hq2[mt >> 1][pt].u[(mt & 1) * 2 + 0] = pk_bf16(hv[0], hv[1]);
            hq2[mt >> 1][pt].u[(mt & 1) * 2 + 1] = pk_bf16(hv[2], hv[3]);
        }
    }

    // ---- layer 3 on MFMA (row-replicated W3: reg r = channel r) ----
    f4v acc3[4] = { zero4, zero4, zero4, zero4 };
    #pragma unroll
    for (int st = 0; st < 2; ++st) {
        Frag a3;
        a3.v = *(const s8v*)(w3t + c15 * 64 + st * 32 + g * 8);
        #pragma unroll
        for (int pt = 0; pt < 4; ++pt)
            acc3[pt] = __builtin_amdgcn_mfma_f32_16x16x32_bf16(
                a3.v, hq2[st][pt].v, acc3[pt], 0, 0, 0);
    }

    float ov[3];
    #pragma unroll
    for (int c = 0; c < 3; ++c) {
        float v = acc3[0][c];
        v = (g == 1) ? acc3[1][c] : v;
        v = (g == 2) ? acc3[2][c] : v;
        v = (g == 3) ? acc3[3][c] : v;
        ov[c] = v + b3[c];
    }
    const int pix = ((yw + g) << 10) + xb + c15;
    out[0 * NPIX + pix] = 1.0f / (1.0f + __expf(-ov[0]));
    out[1 * NPIX + pix] = 1.0f / (1.0f + __expf(-ov[1]));
    out[2 * NPIX + pix] = 1.0f / (1.0f + __expf(-ov[2]));
}

extern "C" void kernel_launch(void* const* d_in, const int* in_sizes, int n_in,
                              void* d_out, int out_size, void* d_ws, size_t ws_size,
                              hipStream_t stream) {
    const float* tables = (const float*)d_in[0];
    const float* W1     = (const float*)d_in[1];
    const float* b1     = (const float*)d_in[2];
    const float* W2     = (const float*)d_in[3];
    const float* b2     = (const float*)d_in[4];
    const float* W3     = (const float*)d_in[5];
    const float* b3     = (const float*)d_in[6];
    float* out          = (float*)d_out;
    float* ws           = (float*)d_ws;

    ResArr res;
    const double growth = exp((log(1024.0) - log(16.0)) / 15.0);
    for (int l = 0; l < NLEV; ++l)
        res.r[l] = (float)floor(16.0 * pow(growth, (double)l));

    hipLaunchKernelGGL(prep_kernel, dim3(1), dim3(256), 0, stream, W1, W2, W3, ws, res);
    hipLaunchKernelGGL(ngp_fused_kernel, dim3(64, 64), dim3(256), 0, stream,
                       tables, b1, b2, b3, ws, out);
}